// Round 1
// baseline (870.307 us; speedup 1.0000x reference)
//
#include <hip/hip_runtime.h>
#include <math.h>

constexpr int B_ = 16;
constexpr int T_ = 10240;
constexpr int C_ = 256;
constexpr int KW = 10;
constexpr int L_ = 2047;
constexpr int N_ = B_ * L_;      // 32752
constexpr int KSTEPS = 12;
constexpr float EPS_ = 1e-5f;

// -------------------- pass 1: conv + relu + BN stats --------------------
__global__ __launch_bounds__(256) void conv_stats_kernel(
    const float* __restrict__ x, const float* __restrict__ cw,
    const float* __restrict__ cb, float* __restrict__ ssum, float* __restrict__ ssq)
{
    const int b  = blockIdx.y;
    const int l0 = blockIdx.x * 128;
    const int cnt = min(128, L_ - l0);
    const int c = threadIdx.x;
    __shared__ float xs[128 * 5 + 8];
    const float* xb = x + (size_t)b * T_;
    for (int i = threadIdx.x; i < cnt * 5 + 5; i += 256) xs[i] = xb[l0 * 5 + i];
    float w[KW];
#pragma unroll
    for (int j = 0; j < KW; ++j) w[j] = cw[c * KW + j];
    const float bias = cb[c];
    __syncthreads();
    float s = 0.f, s2 = 0.f;
    for (int dl = 0; dl < cnt; ++dl) {
        float v = bias;
#pragma unroll
        for (int j = 0; j < KW; ++j) v = fmaf(xs[dl * 5 + j], w[j], v);
        v = fmaxf(v, 0.f);
        s += v;
        s2 = fmaf(v, v, s2);
    }
    atomicAdd(&ssum[c], s);
    atomicAdd(&ssq[c], s2);
}

// -------------------- finalize BN scale/shift --------------------
__global__ void bn_finalize_kernel(const float* __restrict__ ssum, const float* __restrict__ ssq,
                                   const float* __restrict__ gamma, const float* __restrict__ beta,
                                   float* __restrict__ scale, float* __restrict__ shift)
{
    int c = threadIdx.x;
    const float inv_n = 1.0f / (float)N_;
    float mu  = ssum[c] * inv_n;
    float var = ssq[c] * inv_n - mu * mu;
    float sc  = gamma[c] * rsqrtf(var + EPS_);
    scale[c] = sc;
    shift[c] = beta[c] - mu * sc;
}

// -------------------- pass 2: conv + relu + normalize, write Z (N,C) and out0 (B,C,L) ----
__global__ __launch_bounds__(256) void conv_norm_kernel(
    const float* __restrict__ x, const float* __restrict__ cw, const float* __restrict__ cb,
    const float* __restrict__ scale, const float* __restrict__ shift,
    float* __restrict__ Z, float* __restrict__ out0)
{
    const int b  = blockIdx.y;
    const int l0 = blockIdx.x * 128;
    const int cnt = min(128, L_ - l0);
    const int c = threadIdx.x;
    __shared__ float xs[128 * 5 + 8];
    const float* xb = x + (size_t)b * T_;
    for (int i = threadIdx.x; i < cnt * 5 + 5; i += 256) xs[i] = xb[l0 * 5 + i];
    float w[KW];
#pragma unroll
    for (int j = 0; j < KW; ++j) w[j] = cw[c * KW + j];
    const float bias = cb[c];
    const float sc = scale[c], sh = shift[c];
    __syncthreads();
    for (int dl = 0; dl < cnt; ++dl) {
        float v = bias;
#pragma unroll
        for (int j = 0; j < KW; ++j) v = fmaf(xs[dl * 5 + j], w[j], v);
        v = fmaxf(v, 0.f);
        float z = fmaf(v, sc, sh);
        int l = l0 + dl;
        Z[((size_t)(b * L_ + l)) * C_ + c] = z;                 // coalesced across c
        out0[((size_t)(b * C_ + c)) * L_ + l] = z;              // sequential in l per thread
    }
}

// -------------------- q kernel: q_k[i] = z_i^T W_k z_i + b_k . z_i --------------------
// block: 256 threads (4 waves), 16 rows, one k.
// lane i owns W columns 4i..4i+3 (coalesced float4 loads); wave w owns W rows [64w,64w+64).
__global__ __launch_bounds__(256) void q_kernel(
    const float* __restrict__ Z, const float* __restrict__ tw,
    const float* __restrict__ tb, float* __restrict__ qout)
{
    const int k    = blockIdx.y;
    const int row0 = blockIdx.x * 16;
    const float* Wk = tw + (size_t)k * C_ * C_;
    __shared__ float zs[16 * 256];
    __shared__ float qacc[16];

    for (int t = threadIdx.x; t < 16 * 64; t += 256) {
        int r = t >> 6, j4 = (t & 63) << 2;
        *(float4*)&zs[r * 256 + j4] = *(const float4*)&Z[((size_t)(row0 + r)) * C_ + j4];
    }
    if (threadIdx.x < 16) qacc[threadIdx.x] = 0.f;
    __syncthreads();

    const int lane = threadIdx.x & 63;
    const int wave = threadIdx.x >> 6;
    const int j4   = lane << 2;

    float4 acc[16];
#pragma unroll
    for (int r = 0; r < 16; ++r) acc[r] = float4{0.f, 0.f, 0.f, 0.f};

    const int c0 = wave * 64;
    for (int c = c0; c < c0 + 64; ++c) {
        float4 w4 = *(const float4*)&Wk[(size_t)c * C_ + j4];
#pragma unroll
        for (int r = 0; r < 16; ++r) {
            float zc = zs[r * 256 + c];          // LDS broadcast
            acc[r].x = fmaf(w4.x, zc, acc[r].x);
            acc[r].y = fmaf(w4.y, zc, acc[r].y);
            acc[r].z = fmaf(w4.z, zc, acc[r].z);
            acc[r].w = fmaf(w4.w, zc, acc[r].w);
        }
    }

    const float* bbk = tb + k * C_;
    float4 bb4 = *(const float4*)&bbk[j4];
#pragma unroll
    for (int r = 0; r < 16; ++r) {
        float4 z4 = *(float4*)&zs[r * 256 + j4];
        float s = acc[r].x * z4.x + acc[r].y * z4.y + acc[r].z * z4.z + acc[r].w * z4.w;
        if (wave == 0)  // count the bias term exactly once (wave 0's lanes cover all 256 j)
            s += bb4.x * z4.x + bb4.y * z4.y + bb4.z * z4.z + bb4.w * z4.w;
#pragma unroll
        for (int off = 32; off > 0; off >>= 1) s += __shfl_down(s, off);
        if (lane == 0) atomicAdd(&qacc[r], s);
    }
    __syncthreads();
    if (threadIdx.x < 16) qout[(size_t)k * N_ + row0 + threadIdx.x] = qacc[threadIdx.x];
}

// -------------------- loss: gather 11 q's per row, LSE, accumulate --------------------
__global__ __launch_bounds__(256) void loss_kernel(
    const float* __restrict__ qb, const int* __restrict__ perm, float* __restrict__ lacc)
{
    const int k = blockIdx.y + 1;                 // 1..12
    const float* qk = qb + (size_t)(k - 1) * N_;
    const int llen = L_ - k;
    const int nrows = B_ * llen;
    const int idx = blockIdx.x * 256 + threadIdx.x;

    float contrib = 0.f;
    if (idx < nrows) {
        int b = idx / llen;
        int l = k + (idx - b * llen);
        float f[11];
        f[0] = qk[b * L_ + l];
        int pl = perm[l];
#pragma unroll
        for (int n = 0; n < 10; ++n) {
            int b2 = (b + 15 - n) & 15;           // (b - n - 1) mod 16
            f[n + 1] = qk[b2 * L_ + pl];
        }
        float m = f[0];
#pragma unroll
        for (int i = 1; i < 11; ++i) m = fmaxf(m, f[i]);
        float se = 0.f, fs = 0.f;
#pragma unroll
        for (int i = 0; i < 11; ++i) { se += expf(f[i] - m); fs += f[i]; }
        contrib = 11.f * (m + logf(se)) - fs;
    }

    __shared__ float red[4];
#pragma unroll
    for (int off = 32; off > 0; off >>= 1) contrib += __shfl_down(contrib, off);
    const int lane = threadIdx.x & 63;
    const int wave = threadIdx.x >> 6;
    if (lane == 0) red[wave] = contrib;
    __syncthreads();
    if (threadIdx.x == 0) atomicAdd(&lacc[k - 1], red[0] + red[1] + red[2] + red[3]);
}

__global__ void finalize_loss_kernel(const float* __restrict__ lacc, float* __restrict__ out1)
{
    int k = threadIdx.x;
    if (k < KSTEPS) {
        float div = (float)((L_ - 2 * (k + 1)) * B_);
        out1[k] = lacc[k] / div;
    }
}

// -------------------- launch --------------------
extern "C" void kernel_launch(void* const* d_in, const int* in_sizes, int n_in,
                              void* d_out, int out_size, void* d_ws, size_t ws_size,
                              hipStream_t stream)
{
    const float* x     = (const float*)d_in[0];
    const float* cw    = (const float*)d_in[1];
    const float* cb    = (const float*)d_in[2];
    const float* gamma = (const float*)d_in[3];
    const float* beta  = (const float*)d_in[4];
    const float* tw    = (const float*)d_in[5];
    const float* tb    = (const float*)d_in[6];
    const int*   perm  = (const int*)d_in[7];

    float* out0 = (float*)d_out;
    float* out1 = out0 + (size_t)B_ * C_ * L_;

    float* Z     = (float*)d_ws;
    float* q     = Z + (size_t)N_ * C_;
    float* ssum  = q + (size_t)KSTEPS * N_;
    float* ssq   = ssum + C_;
    float* lacc  = ssq + C_;        // 16 floats (12 used)
    float* scale = lacc + 16;
    float* shift = scale + C_;

    hipMemsetAsync(ssum, 0, (C_ + C_ + 16) * sizeof(float), stream);

    dim3 gconv(16, 16);
    conv_stats_kernel<<<gconv, 256, 0, stream>>>(x, cw, cb, ssum, ssq);
    bn_finalize_kernel<<<1, 256, 0, stream>>>(ssum, ssq, gamma, beta, scale, shift);
    conv_norm_kernel<<<gconv, 256, 0, stream>>>(x, cw, cb, scale, shift, Z, out0);

    dim3 gq(N_ / 16, KSTEPS);       // 2047 x 12
    q_kernel<<<gq, 256, 0, stream>>>(Z, tw, tb, q);

    dim3 gl(128, KSTEPS);
    loss_kernel<<<gl, 256, 0, stream>>>(q, perm, lacc);
    finalize_loss_kernel<<<1, 64, 0, stream>>>(lacc, out1);
}

// Round 2
// 270.106 us; speedup vs baseline: 3.2221x; 3.2221x over previous
//
#include <hip/hip_runtime.h>
#include <hip/hip_bf16.h>
#include <math.h>

constexpr int B_ = 16;
constexpr int T_ = 10240;
constexpr int C_ = 256;
constexpr int KW = 10;
constexpr int L_ = 2047;
constexpr int N_ = B_ * L_;      // 32752
constexpr int KSTEPS = 12;
constexpr float EPS_ = 1e-5f;
constexpr int MT = 64;           // rows per q-block
constexpr int ZSTR = 264;        // LDS Z-tile row stride in bf16 elems (16B-aligned, 2-way banks)

typedef short bf16x8 __attribute__((ext_vector_type(8)));
typedef float f32x4  __attribute__((ext_vector_type(4)));

// -------------------- pass 1: conv + relu + BN stats --------------------
__global__ __launch_bounds__(256) void conv_stats_kernel(
    const float* __restrict__ x, const float* __restrict__ cw,
    const float* __restrict__ cb, float* __restrict__ ssum, float* __restrict__ ssq)
{
    const int b  = blockIdx.y;
    const int l0 = blockIdx.x * 128;
    const int cnt = min(128, L_ - l0);
    const int c = threadIdx.x;
    __shared__ float xs[128 * 5 + 8];
    const float* xb = x + (size_t)b * T_;
    for (int i = threadIdx.x; i < cnt * 5 + 5; i += 256) xs[i] = xb[l0 * 5 + i];
    float w[KW];
#pragma unroll
    for (int j = 0; j < KW; ++j) w[j] = cw[c * KW + j];
    const float bias = cb[c];
    __syncthreads();
    float s = 0.f, s2 = 0.f;
    for (int dl = 0; dl < cnt; ++dl) {
        float v = bias;
#pragma unroll
        for (int j = 0; j < KW; ++j) v = fmaf(xs[dl * 5 + j], w[j], v);
        v = fmaxf(v, 0.f);
        s += v;
        s2 = fmaf(v, v, s2);
    }
    atomicAdd(&ssum[c], s);
    atomicAdd(&ssq[c], s2);
}

// -------------------- finalize BN scale/shift --------------------
__global__ void bn_finalize_kernel(const float* __restrict__ ssum, const float* __restrict__ ssq,
                                   const float* __restrict__ gamma, const float* __restrict__ beta,
                                   float* __restrict__ scale, float* __restrict__ shift)
{
    int c = threadIdx.x;
    const float inv_n = 1.0f / (float)N_;
    float mu  = ssum[c] * inv_n;
    float var = ssq[c] * inv_n - mu * mu;
    float sc  = gamma[c] * rsqrtf(var + EPS_);
    scale[c] = sc;
    shift[c] = beta[c] - mu * sc;
}

// -------------------- pass 2: conv + relu + normalize → out0 (f32) + Zb (bf16) ------
__global__ __launch_bounds__(256) void conv_norm_kernel(
    const float* __restrict__ x, const float* __restrict__ cw, const float* __restrict__ cb,
    const float* __restrict__ scale, const float* __restrict__ shift,
    __hip_bfloat16* __restrict__ Zb, float* __restrict__ out0)
{
    const int b  = blockIdx.y;
    const int l0 = blockIdx.x * 128;
    const int cnt = min(128, L_ - l0);
    const int c = threadIdx.x;
    __shared__ float xs[128 * 5 + 8];
    const float* xb = x + (size_t)b * T_;
    for (int i = threadIdx.x; i < cnt * 5 + 5; i += 256) xs[i] = xb[l0 * 5 + i];
    float w[KW];
#pragma unroll
    for (int j = 0; j < KW; ++j) w[j] = cw[c * KW + j];
    const float bias = cb[c];
    const float sc = scale[c], sh = shift[c];
    __syncthreads();
    for (int dl = 0; dl < cnt; ++dl) {
        float v = bias;
#pragma unroll
        for (int j = 0; j < KW; ++j) v = fmaf(xs[dl * 5 + j], w[j], v);
        v = fmaxf(v, 0.f);
        float z = fmaf(v, sc, sh);
        int l = l0 + dl;
        Zb[((size_t)(b * L_ + l)) * C_ + c] = __float2bfloat16(z);
        out0[((size_t)(b * C_ + c)) * L_ + l] = z;
    }
}

// -------------------- W transpose: tr_w (K,C,C) f32 → Wt (K,C,C) bf16, Wt[k][j][c]=W[k][c][j]
__global__ __launch_bounds__(256) void wt_kernel(const float* __restrict__ tw,
                                                 __hip_bfloat16* __restrict__ Wt)
{
    const int k  = blockIdx.z;
    const int c0 = blockIdx.x * 64, j0 = blockIdx.y * 64;
    __shared__ float tile[64][65];
    for (int i = threadIdx.x; i < 64 * 64; i += 256) {
        int c = i >> 6, j = i & 63;
        tile[c][j] = tw[((size_t)k * C_ + (c0 + c)) * C_ + j0 + j];
    }
    __syncthreads();
    for (int i = threadIdx.x; i < 64 * 64; i += 256) {
        int j = i >> 6, c = i & 63;
        Wt[((size_t)k * C_ + (j0 + j)) * C_ + c0 + c] = __float2bfloat16(tile[c][j]);
    }
}

// -------------------- q kernel (MFMA): q_k[i] = rowsum((Z W_k + b) ⊙ Z) --------------
// Block: 256 threads (4 waves), 64 rows, one k, all 256 cols.
// Wave w owns cols [64w, 64w+64): 4 col-tiles × 4 row-tiles of 16x16x32 MFMA.
// A (Z rows) from LDS; B (Wt rows) direct from global/L2, prefetched one K-iter ahead.
__global__ __launch_bounds__(256, 3) void qmfma_kernel(
    const __hip_bfloat16* __restrict__ Zb, const __hip_bfloat16* __restrict__ Wt,
    const float* __restrict__ tb, float* __restrict__ qout)
{
    const int k    = blockIdx.y;
    const int row0 = blockIdx.x * MT;
    const __hip_bfloat16* __restrict__ Wk = Wt + (size_t)k * C_ * C_;

    __shared__ __hip_bfloat16 zs[MT * ZSTR];
    __shared__ float qred[4][MT];

    // ---- stage Z tile (64 rows x 256 bf16), 16B chunks, clamp ragged tail ----
    {
        const int t = threadIdx.x;
#pragma unroll
        for (int i = 0; i < 8; ++i) {
            int chunk = t + i * 256;          // 0..2047
            int r   = chunk >> 5;             // 0..63
            int c16 = chunk & 31;             // 16B unit within row
            int rg  = row0 + r; if (rg > N_ - 1) rg = N_ - 1;
            *(float4*)(zs + r * ZSTR + c16 * 8) =
                *(const float4*)(Zb + (size_t)rg * C_ + c16 * 8);
        }
    }
    __syncthreads();

    const int lane = threadIdx.x & 63;
    const int wave = threadIdx.x >> 6;
    const int n16  = lane & 15;
    const int quad = lane >> 4;

    // B-frag base: col n = 64*wave + ct*16 + n16, k-offset = it*32 + quad*8
    const __hip_bfloat16* __restrict__ wbase =
        Wk + ((size_t)(64 * wave + n16)) * C_ + quad * 8;
    const __hip_bfloat16* __restrict__ abase = zs + n16 * ZSTR + quad * 8;

    f32x4 acc[4][4];
#pragma unroll
    for (int rt = 0; rt < 4; ++rt)
#pragma unroll
        for (int ct = 0; ct < 4; ++ct) acc[rt][ct] = f32x4{0.f, 0.f, 0.f, 0.f};

    bf16x8 bcur[4], bnext[4], afrag[4];
#pragma unroll
    for (int ct = 0; ct < 4; ++ct)
        bcur[ct] = *(const bf16x8*)(wbase + ct * 16 * C_);

#pragma unroll
    for (int it = 0; it < 8; ++it) {
        if (it < 7) {
#pragma unroll
            for (int ct = 0; ct < 4; ++ct)
                bnext[ct] = *(const bf16x8*)(wbase + ct * 16 * C_ + (it + 1) * 32);
        }
#pragma unroll
        for (int rt = 0; rt < 4; ++rt)
            afrag[rt] = *(const bf16x8*)(abase + rt * 16 * ZSTR + it * 32);
#pragma unroll
        for (int rt = 0; rt < 4; ++rt)
#pragma unroll
            for (int ct = 0; ct < 4; ++ct)
                acc[rt][ct] = __builtin_amdgcn_mfma_f32_16x16x32_bf16(
                    afrag[rt], bcur[ct], acc[rt][ct], 0, 0, 0);
#pragma unroll
        for (int ct = 0; ct < 4; ++ct) bcur[ct] = bnext[ct];
    }

    // ---- epilogue: q partial = Σ_cols (Y + b) * z ----
    float bcol[4];
#pragma unroll
    for (int ct = 0; ct < 4; ++ct)
        bcol[ct] = tb[k * C_ + 64 * wave + ct * 16 + n16];

#pragma unroll
    for (int rt = 0; rt < 4; ++rt) {
#pragma unroll
        for (int r = 0; r < 4; ++r) {
            const int row = rt * 16 + quad * 4 + r;
            float s = 0.f;
#pragma unroll
            for (int ct = 0; ct < 4; ++ct) {
                float z = (float)zs[row * ZSTR + 64 * wave + ct * 16 + n16];
                s = fmaf(acc[rt][ct][r] + bcol[ct], z, s);
            }
            s += __shfl_xor(s, 1);
            s += __shfl_xor(s, 2);
            s += __shfl_xor(s, 4);
            s += __shfl_xor(s, 8);
            if (n16 == 0) qred[wave][row] = s;
        }
    }
    __syncthreads();
    if (threadIdx.x < MT) {
        int r  = threadIdx.x;
        int rg = row0 + r;
        if (rg < N_)
            qout[(size_t)k * N_ + rg] = qred[0][r] + qred[1][r] + qred[2][r] + qred[3][r];
    }
}

// -------------------- loss: gather 11 q's per row, LSE, accumulate --------------------
__global__ __launch_bounds__(256) void loss_kernel(
    const float* __restrict__ qb, const int* __restrict__ perm, float* __restrict__ lacc)
{
    const int k = blockIdx.y + 1;                 // 1..12
    const float* qk = qb + (size_t)(k - 1) * N_;
    const int llen = L_ - k;
    const int nrows = B_ * llen;
    const int idx = blockIdx.x * 256 + threadIdx.x;

    float contrib = 0.f;
    if (idx < nrows) {
        int b = idx / llen;
        int l = k + (idx - b * llen);
        float f[11];
        f[0] = qk[b * L_ + l];
        int pl = perm[l];
#pragma unroll
        for (int n = 0; n < 10; ++n) {
            int b2 = (b + 15 - n) & 15;           // (b - n - 1) mod 16
            f[n + 1] = qk[b2 * L_ + pl];
        }
        float m = f[0];
#pragma unroll
        for (int i = 1; i < 11; ++i) m = fmaxf(m, f[i]);
        float se = 0.f, fs = 0.f;
#pragma unroll
        for (int i = 0; i < 11; ++i) { se += expf(f[i] - m); fs += f[i]; }
        contrib = 11.f * (m + logf(se)) - fs;
    }

    __shared__ float red[4];
#pragma unroll
    for (int off = 32; off > 0; off >>= 1) contrib += __shfl_down(contrib, off);
    const int lane = threadIdx.x & 63;
    const int wave = threadIdx.x >> 6;
    if (lane == 0) red[wave] = contrib;
    __syncthreads();
    if (threadIdx.x == 0) atomicAdd(&lacc[k - 1], red[0] + red[1] + red[2] + red[3]);
}

__global__ void finalize_loss_kernel(const float* __restrict__ lacc, float* __restrict__ out1)
{
    int k = threadIdx.x;
    if (k < KSTEPS) {
        float div = (float)((L_ - 2 * (k + 1)) * B_);
        out1[k] = lacc[k] / div;
    }
}

// -------------------- launch --------------------
extern "C" void kernel_launch(void* const* d_in, const int* in_sizes, int n_in,
                              void* d_out, int out_size, void* d_ws, size_t ws_size,
                              hipStream_t stream)
{
    const float* x     = (const float*)d_in[0];
    const float* cw    = (const float*)d_in[1];
    const float* cb    = (const float*)d_in[2];
    const float* gamma = (const float*)d_in[3];
    const float* beta  = (const float*)d_in[4];
    const float* tw    = (const float*)d_in[5];
    const float* tb    = (const float*)d_in[6];
    const int*   perm  = (const int*)d_in[7];

    float* out0 = (float*)d_out;
    float* out1 = out0 + (size_t)B_ * C_ * L_;

    char* ws = (char*)d_ws;
    __hip_bfloat16* Zb = (__hip_bfloat16*)ws;                 ws += (size_t)N_ * C_ * 2;       // 16.77 MB
    __hip_bfloat16* Wt = (__hip_bfloat16*)ws;                 ws += (size_t)KSTEPS * C_ * C_ * 2; // 1.57 MB
    float* q     = (float*)ws;                                ws += (size_t)KSTEPS * N_ * 4;   // 1.57 MB
    float* ssum  = (float*)ws;                                ws += C_ * 4;
    float* ssq   = (float*)ws;                                ws += C_ * 4;
    float* lacc  = (float*)ws;                                ws += 16 * 4;
    float* scale = (float*)ws;                                ws += C_ * 4;
    float* shift = (float*)ws;                                ws += C_ * 4;

    hipMemsetAsync(ssum, 0, (C_ + C_ + 16) * sizeof(float), stream);

    dim3 gconv(16, 16);
    conv_stats_kernel<<<gconv, 256, 0, stream>>>(x, cw, cb, ssum, ssq);
    bn_finalize_kernel<<<1, 256, 0, stream>>>(ssum, ssq, gamma, beta, scale, shift);
    conv_norm_kernel<<<gconv, 256, 0, stream>>>(x, cw, cb, scale, shift, Zb, out0);

    dim3 gwt(4, 4, KSTEPS);
    wt_kernel<<<gwt, 256, 0, stream>>>(tw, Wt);

    dim3 gq((N_ + MT - 1) / MT, KSTEPS);      // 512 x 12
    qmfma_kernel<<<gq, 256, 0, stream>>>(Zb, Wt, tb, q);

    dim3 gl(128, KSTEPS);
    loss_kernel<<<gl, 256, 0, stream>>>(q, perm, lacc);
    finalize_loss_kernel<<<1, 64, 0, stream>>>(lacc, out1);
}

// Round 3
// 224.523 us; speedup vs baseline: 3.8762x; 1.2030x over previous
//
#include <hip/hip_runtime.h>
#include <hip/hip_bf16.h>
#include <math.h>

constexpr int B_ = 16;
constexpr int T_ = 10240;
constexpr int C_ = 256;
constexpr int KW = 10;
constexpr int L_ = 2047;
constexpr int N_ = B_ * L_;      // 32752
constexpr int KSTEPS = 12;
constexpr float EPS_ = 1e-5f;
constexpr int ZSTR = 264;        // LDS Z-tile row stride (bf16 elems), 16B-aligned
constexpr int QSTR = 32768;      // per-k stride of transposed q (2048*16)

typedef short bf16x8 __attribute__((ext_vector_type(8)));
typedef float f32x4  __attribute__((ext_vector_type(4)));

// -------------------- pass 1: conv + relu + BN stats --------------------
__global__ __launch_bounds__(256) void conv_stats_kernel(
    const float* __restrict__ x, const float* __restrict__ cw,
    const float* __restrict__ cb, float* __restrict__ ssum, float* __restrict__ ssq)
{
    const int b  = blockIdx.y;
    const int l0 = blockIdx.x * 128;
    const int cnt = min(128, L_ - l0);
    const int c = threadIdx.x;
    __shared__ float xs[128 * 5 + 8];
    const float* xb = x + (size_t)b * T_;
    for (int i = threadIdx.x; i < cnt * 5 + 5; i += 256) xs[i] = xb[l0 * 5 + i];
    float w[KW];
#pragma unroll
    for (int j = 0; j < KW; ++j) w[j] = cw[c * KW + j];
    const float bias = cb[c];
    __syncthreads();
    float s = 0.f, s2 = 0.f;
    for (int dl = 0; dl < cnt; ++dl) {
        float v = bias;
#pragma unroll
        for (int j = 0; j < KW; ++j) v = fmaf(xs[dl * 5 + j], w[j], v);
        v = fmaxf(v, 0.f);
        s += v;
        s2 = fmaf(v, v, s2);
    }
    atomicAdd(&ssum[c], s);
    atomicAdd(&ssq[c], s2);
}

// -------------------- finalize BN scale/shift --------------------
__global__ void bn_finalize_kernel(const float* __restrict__ ssum, const float* __restrict__ ssq,
                                   const float* __restrict__ gamma, const float* __restrict__ beta,
                                   float* __restrict__ scale, float* __restrict__ shift)
{
    int c = threadIdx.x;
    const float inv_n = 1.0f / (float)N_;
    float mu  = ssum[c] * inv_n;
    float var = ssq[c] * inv_n - mu * mu;
    float sc  = gamma[c] * rsqrtf(var + EPS_);
    scale[c] = sc;
    shift[c] = beta[c] - mu * sc;
}

// -------------------- pass 2: conv + relu + normalize → out0 (f32, LDS-transposed) + Zb (bf16)
__global__ __launch_bounds__(256) void conv_norm_kernel(
    const float* __restrict__ x, const float* __restrict__ cw, const float* __restrict__ cb,
    const float* __restrict__ scale, const float* __restrict__ shift,
    __hip_bfloat16* __restrict__ Zb, float* __restrict__ out0)
{
    const int b  = blockIdx.y;
    const int l0 = blockIdx.x * 64;
    const int cnt = min(64, L_ - l0);
    const int c = threadIdx.x;
    __shared__ float xs[64 * 5 + 16];
    __shared__ float zt[64][261];
    const float* xb = x + (size_t)b * T_;
    for (int i = threadIdx.x; i < cnt * 5 + 5; i += 256) xs[i] = xb[l0 * 5 + i];
    float w[KW];
#pragma unroll
    for (int j = 0; j < KW; ++j) w[j] = cw[c * KW + j];
    const float bias = cb[c];
    const float sc = scale[c], sh = shift[c];
    __syncthreads();
    for (int dl = 0; dl < cnt; ++dl) {
        float v = bias;
#pragma unroll
        for (int j = 0; j < KW; ++j) v = fmaf(xs[dl * 5 + j], w[j], v);
        v = fmaxf(v, 0.f);
        float z = fmaf(v, sc, sh);
        int l = l0 + dl;
        Zb[((size_t)(b * L_ + l)) * C_ + c] = __float2bfloat16(z);   // coalesced across c
        zt[dl][c] = z;
    }
    __syncthreads();
    // out0 writes: 16-lane groups cover 16 consecutive l of one c-row
    const int l4  = threadIdx.x & 15;
    const int crb = threadIdx.x >> 4;
#pragma unroll
    for (int seg = 0; seg < 4; ++seg) {
        int ll = seg * 16 + l4;
        bool valid = ll < cnt;
#pragma unroll
        for (int i = 0; i < 16; ++i) {
            int cr = crb + 16 * i;
            if (valid)
                out0[((size_t)(b * C_ + cr)) * L_ + l0 + ll] = zt[ll][cr];
        }
    }
}

// -------------------- W transpose: tr_w (K,C,C) f32 → Wt (K,C,C) bf16, Wt[k][j][c]=W[k][c][j]
__global__ __launch_bounds__(256) void wt_kernel(const float* __restrict__ tw,
                                                 __hip_bfloat16* __restrict__ Wt)
{
    const int k  = blockIdx.z;
    const int c0 = blockIdx.x * 64, j0 = blockIdx.y * 64;
    __shared__ float tile[64][65];
    for (int i = threadIdx.x; i < 64 * 64; i += 256) {
        int c = i >> 6, j = i & 63;
        tile[c][j] = tw[((size_t)k * C_ + (c0 + c)) * C_ + j0 + j];
    }
    __syncthreads();
    for (int i = threadIdx.x; i < 64 * 64; i += 256) {
        int j = i >> 6, c = i & 63;
        Wt[((size_t)k * C_ + (j0 + j)) * C_ + c0 + c] = __float2bfloat16(tile[c][j]);
    }
}

// -------------------- q kernel (MFMA, W-resident): q_k[i] = rowsum((Z W_k + b) ⊙ Z) ----
// Grid (128, 12): block = one k, 8 tiles of 32 rows. 256 thr, wave w owns cols [64w,64w+64).
// W held in 128 VGPRs/lane for the whole block; Z tiles double-buffered through LDS.
// MFMA operands swapped: D = Y^T so acc (quad,reg) axis = W-col → b64 epilogue reads.
__global__ __launch_bounds__(256, 2) void qmfma_kernel(
    const __hip_bfloat16* __restrict__ Zb, const __hip_bfloat16* __restrict__ Wt,
    const float* __restrict__ tb, float* __restrict__ qt)
{
    const int k   = blockIdx.y;
    const int grp = blockIdx.x;
    const __hip_bfloat16* __restrict__ Wk = Wt + (size_t)k * C_ * C_;

    __shared__ __hip_bfloat16 zs[2][32 * ZSTR];
    __shared__ float qred[4][32];

    const int tid  = threadIdx.x;
    const int lane = tid & 63, wave = tid >> 6;
    const int n16  = lane & 15, quad = lane >> 4;

    // ---- W resident: col = 64*wave + ct*16 + n16 ; kk = it*32 + quad*8 + j ----
    bf16x8 wfrag[4][8];
    {
        const __hip_bfloat16* wb = Wk + ((size_t)(64 * wave + n16)) * C_ + quad * 8;
#pragma unroll
        for (int ct = 0; ct < 4; ++ct)
#pragma unroll
            for (int it = 0; it < 8; ++it)
                wfrag[ct][it] = *(const bf16x8*)(wb + ct * 16 * C_ + it * 32);
    }
    float4 bias4[4];
#pragma unroll
    for (int ct = 0; ct < 4; ++ct)
        bias4[ct] = *(const float4*)(tb + k * C_ + 64 * wave + ct * 16 + quad * 4);

    const int row0 = grp * 8 * 32;
    float4 greg[4];

    // stage tile 0
#pragma unroll
    for (int i = 0; i < 4; ++i) {
        int chunk = tid + i * 256;
        int r = chunk >> 5, c16 = chunk & 31;
        int rg = row0 + r; if (rg > N_ - 1) rg = N_ - 1;
        greg[i] = *(const float4*)(Zb + (size_t)rg * C_ + c16 * 8);
    }
#pragma unroll
    for (int i = 0; i < 4; ++i) {
        int chunk = tid + i * 256;
        int r = chunk >> 5, c16 = chunk & 31;
        *(float4*)((__hip_bfloat16*)zs[0] + r * ZSTR + c16 * 8) = greg[i];
    }
    __syncthreads();

    for (int t = 0; t < 8; ++t) {
        const int p = t & 1;

        if (t < 7) {
            int r0 = row0 + (t + 1) * 32;
#pragma unroll
            for (int i = 0; i < 4; ++i) {
                int chunk = tid + i * 256;
                int r = chunk >> 5, c16 = chunk & 31;
                int rg = r0 + r; if (rg > N_ - 1) rg = N_ - 1;
                greg[i] = *(const float4*)(Zb + (size_t)rg * C_ + c16 * 8);
            }
        }

        f32x4 acc[2][4];
#pragma unroll
        for (int rt = 0; rt < 2; ++rt)
#pragma unroll
            for (int ct = 0; ct < 4; ++ct) acc[rt][ct] = f32x4{0.f, 0.f, 0.f, 0.f};

        const __hip_bfloat16* zb0 = (const __hip_bfloat16*)zs[p] + n16 * ZSTR + quad * 8;
#pragma unroll
        for (int it = 0; it < 8; ++it) {
            bf16x8 zf0 = *(const bf16x8*)(zb0 + it * 32);
            bf16x8 zf1 = *(const bf16x8*)(zb0 + 16 * ZSTR + it * 32);
#pragma unroll
            for (int ct = 0; ct < 4; ++ct) {
                acc[0][ct] = __builtin_amdgcn_mfma_f32_16x16x32_bf16(
                    wfrag[ct][it], zf0, acc[0][ct], 0, 0, 0);
                acc[1][ct] = __builtin_amdgcn_mfma_f32_16x16x32_bf16(
                    wfrag[ct][it], zf1, acc[1][ct], 0, 0, 0);
            }
        }

        // ---- epilogue: per lane, zrow = rt*16+n16 ; wcols = 64w + ct*16 + quad*4 + r ----
#pragma unroll
        for (int rt = 0; rt < 2; ++rt) {
            float s = 0.f;
#pragma unroll
            for (int ct = 0; ct < 4; ++ct) {
                const __hip_bfloat16* zp = (const __hip_bfloat16*)zs[p]
                    + (rt * 16 + n16) * ZSTR + 64 * wave + ct * 16 + quad * 4;
                uint2 zz = *(const uint2*)zp;
                float z0 = __uint_as_float(zz.x << 16);
                float z1 = __uint_as_float(zz.x & 0xffff0000u);
                float z2 = __uint_as_float(zz.y << 16);
                float z3 = __uint_as_float(zz.y & 0xffff0000u);
                s = fmaf(acc[rt][ct][0] + bias4[ct].x, z0, s);
                s = fmaf(acc[rt][ct][1] + bias4[ct].y, z1, s);
                s = fmaf(acc[rt][ct][2] + bias4[ct].z, z2, s);
                s = fmaf(acc[rt][ct][3] + bias4[ct].w, z3, s);
            }
            s += __shfl_xor(s, 16);
            s += __shfl_xor(s, 32);
            if (lane < 16) qred[wave][rt * 16 + n16] = s;
        }
        __syncthreads();

        if (tid < 32) {
            int rg = row0 + t * 32 + tid;
            if (rg < N_) {
                float qv = qred[0][tid] + qred[1][tid] + qred[2][tid] + qred[3][tid];
                int b = rg / L_;
                int l = rg - b * L_;
                qt[(size_t)k * QSTR + (l << 4) + b] = qv;
            }
        }
        if (t < 7) {
#pragma unroll
            for (int i = 0; i < 4; ++i) {
                int chunk = tid + i * 256;
                int r = chunk >> 5, c16 = chunk & 31;
                *(float4*)((__hip_bfloat16*)zs[1 - p] + r * ZSTR + c16 * 8) = greg[i];
            }
        }
        __syncthreads();
    }
}

// -------------------- loss: coalesced gathers from transposed q, LSE, accumulate ------
__global__ __launch_bounds__(256) void loss_kernel(
    const float* __restrict__ qt, const int* __restrict__ perm, float* __restrict__ lacc)
{
    const int k = blockIdx.y + 1;                 // 1..12
    const float* qk = qt + (size_t)(k - 1) * QSTR;
    const int nval = B_ * (L_ - k);
    const int idx = blockIdx.x * 256 + threadIdx.x;

    float contrib = 0.f;
    if (idx < nval) {
        int b = idx & 15;
        int l = k + (idx >> 4);
        float f0 = qk[(l << 4) | b];
        int pl = perm[l];
        const float* qn = qk + ((size_t)pl << 4);
        float f[10];
#pragma unroll
        for (int n = 0; n < 10; ++n) f[n] = qn[(b + 15 - n) & 15];
        float m = f0;
#pragma unroll
        for (int i = 0; i < 10; ++i) m = fmaxf(m, f[i]);
        float se = expf(f0 - m), fs = f0;
#pragma unroll
        for (int i = 0; i < 10; ++i) { se += expf(f[i] - m); fs += f[i]; }
        contrib = 11.f * (m + logf(se)) - fs;
    }

    __shared__ float red[4];
#pragma unroll
    for (int off = 32; off > 0; off >>= 1) contrib += __shfl_down(contrib, off);
    const int lane = threadIdx.x & 63;
    const int wave = threadIdx.x >> 6;
    if (lane == 0) red[wave] = contrib;
    __syncthreads();
    if (threadIdx.x == 0) atomicAdd(&lacc[k - 1], red[0] + red[1] + red[2] + red[3]);
}

__global__ void finalize_loss_kernel(const float* __restrict__ lacc, float* __restrict__ out1)
{
    int k = threadIdx.x;
    if (k < KSTEPS) {
        float div = (float)((L_ - 2 * (k + 1)) * B_);
        out1[k] = lacc[k] / div;
    }
}

// -------------------- launch --------------------
extern "C" void kernel_launch(void* const* d_in, const int* in_sizes, int n_in,
                              void* d_out, int out_size, void* d_ws, size_t ws_size,
                              hipStream_t stream)
{
    const float* x     = (const float*)d_in[0];
    const float* cw    = (const float*)d_in[1];
    const float* cb    = (const float*)d_in[2];
    const float* gamma = (const float*)d_in[3];
    const float* beta  = (const float*)d_in[4];
    const float* tw    = (const float*)d_in[5];
    const float* tb    = (const float*)d_in[6];
    const int*   perm  = (const int*)d_in[7];

    float* out0 = (float*)d_out;
    float* out1 = out0 + (size_t)B_ * C_ * L_;

    char* ws = (char*)d_ws;
    __hip_bfloat16* Zb = (__hip_bfloat16*)ws;   ws += (size_t)N_ * C_ * 2;
    __hip_bfloat16* Wt = (__hip_bfloat16*)ws;   ws += (size_t)KSTEPS * C_ * C_ * 2;
    float* qt    = (float*)ws;                  ws += (size_t)KSTEPS * QSTR * 4;
    float* ssum  = (float*)ws;                  ws += C_ * 4;
    float* ssq   = (float*)ws;                  ws += C_ * 4;
    float* lacc  = (float*)ws;                  ws += 64 * 4;
    float* scale = (float*)ws;                  ws += C_ * 4;
    float* shift = (float*)ws;                  ws += C_ * 4;

    hipMemsetAsync(ssum, 0, (C_ + C_ + 64) * sizeof(float), stream);

    dim3 gstat(16, 16);
    conv_stats_kernel<<<gstat, 256, 0, stream>>>(x, cw, cb, ssum, ssq);
    bn_finalize_kernel<<<1, 256, 0, stream>>>(ssum, ssq, gamma, beta, scale, shift);

    dim3 gcv(32, 16);
    conv_norm_kernel<<<gcv, 256, 0, stream>>>(x, cw, cb, scale, shift, Zb, out0);

    dim3 gwt(4, 4, KSTEPS);
    wt_kernel<<<gwt, 256, 0, stream>>>(tw, Wt);

    dim3 gq(128, KSTEPS);
    qmfma_kernel<<<gq, 256, 0, stream>>>(Zb, Wt, tb, qt);

    dim3 gl(128, KSTEPS);
    loss_kernel<<<gl, 256, 0, stream>>>(qt, perm, lacc);
    finalize_loss_kernel<<<1, 64, 0, stream>>>(lacc, out1);
}

// Round 4
// 204.102 us; speedup vs baseline: 4.2641x; 1.1001x over previous
//
#include <hip/hip_runtime.h>
#include <hip/hip_bf16.h>
#include <math.h>

constexpr int B_ = 16;
constexpr int T_ = 10240;
constexpr int C_ = 256;
constexpr int KW = 10;
constexpr int L_ = 2047;
constexpr int N_ = B_ * L_;      // 32752
constexpr int KSTEPS = 12;
constexpr float EPS_ = 1e-5f;
constexpr int ZSTR = 264;        // LDS Z-tile row stride (bf16 elems), 16B-aligned
constexpr int QSTR = 32768;      // per-k stride of transposed q (2048*16)

typedef short bf16x8 __attribute__((ext_vector_type(8)));
typedef float f32x4  __attribute__((ext_vector_type(4)));

// -------------------- pass 1: conv + relu + BN stats --------------------
__global__ __launch_bounds__(256) void conv_stats_kernel(
    const float* __restrict__ x, const float* __restrict__ cw,
    const float* __restrict__ cb, float* __restrict__ ssum, float* __restrict__ ssq)
{
    const int b  = blockIdx.y;
    const int l0 = blockIdx.x * 128;
    const int cnt = min(128, L_ - l0);
    const int c = threadIdx.x;
    __shared__ float xs[128 * 5 + 8];
    const float* xb = x + (size_t)b * T_;
    for (int i = threadIdx.x; i < cnt * 5 + 5; i += 256) xs[i] = xb[l0 * 5 + i];
    float w[KW];
#pragma unroll
    for (int j = 0; j < KW; ++j) w[j] = cw[c * KW + j];
    const float bias = cb[c];
    __syncthreads();
    float s = 0.f, s2 = 0.f;
    for (int dl = 0; dl < cnt; ++dl) {
        float v = bias;
#pragma unroll
        for (int j = 0; j < KW; ++j) v = fmaf(xs[dl * 5 + j], w[j], v);
        v = fmaxf(v, 0.f);
        s += v;
        s2 = fmaf(v, v, s2);
    }
    atomicAdd(&ssum[c], s);
    atomicAdd(&ssq[c], s2);
}

// -------------------- finalize BN scale/shift --------------------
__global__ void bn_finalize_kernel(const float* __restrict__ ssum, const float* __restrict__ ssq,
                                   const float* __restrict__ gamma, const float* __restrict__ beta,
                                   float* __restrict__ scale, float* __restrict__ shift)
{
    int c = threadIdx.x;
    const float inv_n = 1.0f / (float)N_;
    float mu  = ssum[c] * inv_n;
    float var = ssq[c] * inv_n - mu * mu;
    float sc  = gamma[c] * rsqrtf(var + EPS_);
    scale[c] = sc;
    shift[c] = beta[c] - mu * sc;
}

// -------------------- pass 2: conv + relu + normalize → out0 (f32, LDS-transposed) + Zb (bf16)
__global__ __launch_bounds__(256) void conv_norm_kernel(
    const float* __restrict__ x, const float* __restrict__ cw, const float* __restrict__ cb,
    const float* __restrict__ scale, const float* __restrict__ shift,
    __hip_bfloat16* __restrict__ Zb, float* __restrict__ out0)
{
    const int b  = blockIdx.y;
    const int l0 = blockIdx.x * 64;
    const int cnt = min(64, L_ - l0);
    const int c = threadIdx.x;
    __shared__ float xs[64 * 5 + 16];
    __shared__ float zt[64][261];
    const float* xb = x + (size_t)b * T_;
    for (int i = threadIdx.x; i < cnt * 5 + 5; i += 256) xs[i] = xb[l0 * 5 + i];
    float w[KW];
#pragma unroll
    for (int j = 0; j < KW; ++j) w[j] = cw[c * KW + j];
    const float bias = cb[c];
    const float sc = scale[c], sh = shift[c];
    __syncthreads();
    for (int dl = 0; dl < cnt; ++dl) {
        float v = bias;
#pragma unroll
        for (int j = 0; j < KW; ++j) v = fmaf(xs[dl * 5 + j], w[j], v);
        v = fmaxf(v, 0.f);
        float z = fmaf(v, sc, sh);
        int l = l0 + dl;
        Zb[((size_t)(b * L_ + l)) * C_ + c] = __float2bfloat16(z);   // coalesced across c
        zt[dl][c] = z;
    }
    __syncthreads();
    // out0 writes: 16-lane groups cover 16 consecutive l of one c-row
    const int l4  = threadIdx.x & 15;
    const int crb = threadIdx.x >> 4;
#pragma unroll
    for (int seg = 0; seg < 4; ++seg) {
        int ll = seg * 16 + l4;
        bool valid = ll < cnt;
#pragma unroll
        for (int i = 0; i < 16; ++i) {
            int cr = crb + 16 * i;
            if (valid)
                out0[((size_t)(b * C_ + cr)) * L_ + l0 + ll] = zt[ll][cr];
        }
    }
}

// -------------------- W transpose: tr_w (K,C,C) f32 → Wt (K,C,C) bf16, Wt[k][j][c]=W[k][c][j]
__global__ __launch_bounds__(256) void wt_kernel(const float* __restrict__ tw,
                                                 __hip_bfloat16* __restrict__ Wt)
{
    const int k  = blockIdx.z;
    const int c0 = blockIdx.x * 64, j0 = blockIdx.y * 64;
    __shared__ float tile[64][65];
    for (int i = threadIdx.x; i < 64 * 64; i += 256) {
        int c = i >> 6, j = i & 63;
        tile[c][j] = tw[((size_t)k * C_ + (c0 + c)) * C_ + j0 + j];
    }
    __syncthreads();
    for (int i = threadIdx.x; i < 64 * 64; i += 256) {
        int j = i >> 6, c = i & 63;
        Wt[((size_t)k * C_ + (j0 + j)) * C_ + c0 + c] = __float2bfloat16(tile[c][j]);
    }
}

// -------------------- q kernel (MFMA, W-resident, 1 barrier/tile): ------------------
// q_k[i] = rowsum((Z W_k + b) ⊙ Z).  Grid (128,12): block = one k, 8 tiles × 32 rows.
// 4 waves × 64 cols (W in 128 VGPRs). Per-wave q partials go to a private LDS slice
// (no per-tile cross-wave reduce); single block-end reduction writes transposed qt.
__global__ __launch_bounds__(256, 2) void qmfma_kernel(
    const __hip_bfloat16* __restrict__ Zb, const __hip_bfloat16* __restrict__ Wt,
    const float* __restrict__ tb, float* __restrict__ qt)
{
    const int k   = blockIdx.y;
    const int grp = blockIdx.x;
    const __hip_bfloat16* __restrict__ Wk = Wt + (size_t)k * C_ * C_;

    __shared__ __hip_bfloat16 zs[2][32 * ZSTR];
    __shared__ float qacc[4][256];

    const int tid  = threadIdx.x;
    const int lane = tid & 63, wave = tid >> 6;
    const int n16  = lane & 15, quad = lane >> 4;

    // ---- W resident: col = 64*wave + ct*16 + n16 ; kk = it*32 + quad*8 + j ----
    bf16x8 wfrag[4][8];
    {
        const __hip_bfloat16* wb = Wk + ((size_t)(64 * wave + n16)) * C_ + quad * 8;
#pragma unroll
        for (int ct = 0; ct < 4; ++ct)
#pragma unroll
            for (int it = 0; it < 8; ++it)
                wfrag[ct][it] = *(const bf16x8*)(wb + ct * 16 * C_ + it * 32);
    }
    float4 bias4[4];
#pragma unroll
    for (int ct = 0; ct < 4; ++ct)
        bias4[ct] = *(const float4*)(tb + k * C_ + 64 * wave + ct * 16 + quad * 4);

    const int row0 = grp * 8 * 32;
    float4 greg[4];

    // stage tile 0 (32 rows × 256 bf16 = 1024 16B-chunks, 4 per thread)
#pragma unroll
    for (int i = 0; i < 4; ++i) {
        int chunk = tid + i * 256;
        int r = chunk >> 5, c16 = chunk & 31;
        int rg = row0 + r; if (rg > N_ - 1) rg = N_ - 1;
        greg[i] = *(const float4*)(Zb + (size_t)rg * C_ + c16 * 8);
    }
#pragma unroll
    for (int i = 0; i < 4; ++i) {
        int chunk = tid + i * 256;
        int r = chunk >> 5, c16 = chunk & 31;
        *(float4*)((__hip_bfloat16*)zs[0] + r * ZSTR + c16 * 8) = greg[i];
    }
    __syncthreads();

    for (int t = 0; t < 8; ++t) {
        const int p = t & 1;

        // prefetch next tile (global → regs); hidden under this tile's MFMA
        if (t < 7) {
            int r0 = row0 + (t + 1) * 32;
#pragma unroll
            for (int i = 0; i < 4; ++i) {
                int chunk = tid + i * 256;
                int r = chunk >> 5, c16 = chunk & 31;
                int rg = r0 + r; if (rg > N_ - 1) rg = N_ - 1;
                greg[i] = *(const float4*)(Zb + (size_t)rg * C_ + c16 * 8);
            }
        }

        f32x4 acc[2][4];
#pragma unroll
        for (int rt = 0; rt < 2; ++rt)
#pragma unroll
            for (int ct = 0; ct < 4; ++ct) acc[rt][ct] = f32x4{0.f, 0.f, 0.f, 0.f};

        const __hip_bfloat16* zb0 = (const __hip_bfloat16*)zs[p] + n16 * ZSTR + quad * 8;
#pragma unroll
        for (int it = 0; it < 8; ++it) {
            bf16x8 zf0 = *(const bf16x8*)(zb0 + it * 32);
            bf16x8 zf1 = *(const bf16x8*)(zb0 + 16 * ZSTR + it * 32);
#pragma unroll
            for (int ct = 0; ct < 4; ++ct) {
                acc[0][ct] = __builtin_amdgcn_mfma_f32_16x16x32_bf16(
                    wfrag[ct][it], zf0, acc[0][ct], 0, 0, 0);
                acc[1][ct] = __builtin_amdgcn_mfma_f32_16x16x32_bf16(
                    wfrag[ct][it], zf1, acc[1][ct], 0, 0, 0);
            }
        }

        // ---- epilogue: zrow = rt*16+n16 ; wcols = 64w + ct*16 + quad*4 + r ----
#pragma unroll
        for (int rt = 0; rt < 2; ++rt) {
            float s = 0.f;
#pragma unroll
            for (int ct = 0; ct < 4; ++ct) {
                const __hip_bfloat16* zp = (const __hip_bfloat16*)zs[p]
                    + (rt * 16 + n16) * ZSTR + 64 * wave + ct * 16 + quad * 4;
                uint2 zz = *(const uint2*)zp;
                float z0 = __uint_as_float(zz.x << 16);
                float z1 = __uint_as_float(zz.x & 0xffff0000u);
                float z2 = __uint_as_float(zz.y << 16);
                float z3 = __uint_as_float(zz.y & 0xffff0000u);
                s = fmaf(acc[rt][ct][0] + bias4[ct].x, z0, s);
                s = fmaf(acc[rt][ct][1] + bias4[ct].y, z1, s);
                s = fmaf(acc[rt][ct][2] + bias4[ct].z, z2, s);
                s = fmaf(acc[rt][ct][3] + bias4[ct].w, z3, s);
            }
            s += __shfl_xor(s, 16);
            s += __shfl_xor(s, 32);
            if (lane < 16) qacc[wave][t * 32 + rt * 16 + n16] = s;   // wave-private slice
        }

        // write prefetched tile into the inactive buffer (prev readers synced last barrier)
        if (t < 7) {
#pragma unroll
            for (int i = 0; i < 4; ++i) {
                int chunk = tid + i * 256;
                int r = chunk >> 5, c16 = chunk & 31;
                *(float4*)((__hip_bfloat16*)zs[1 - p] + r * ZSTR + c16 * 8) = greg[i];
            }
        }
        __syncthreads();
    }

    // ---- block-end: reduce 4 wave partials per row, write transposed qt ----
    {
        int r  = tid;
        int rg = row0 + r;
        if (rg < N_) {
            float qv = qacc[0][r] + qacc[1][r] + qacc[2][r] + qacc[3][r];
            int b = rg / L_;
            int l = rg - b * L_;
            qt[(size_t)k * QSTR + (l << 4) + b] = qv;
        }
    }
}

// -------------------- loss: coalesced gathers from transposed q, LSE, accumulate ------
__global__ __launch_bounds__(256) void loss_kernel(
    const float* __restrict__ qt, const int* __restrict__ perm, float* __restrict__ lacc)
{
    const int k = blockIdx.y + 1;                 // 1..12
    const float* qk = qt + (size_t)(k - 1) * QSTR;
    const int nval = B_ * (L_ - k);
    const int idx = blockIdx.x * 256 + threadIdx.x;

    float contrib = 0.f;
    if (idx < nval) {
        int b = idx & 15;
        int l = k + (idx >> 4);
        float f0 = qk[(l << 4) | b];
        int pl = perm[l];
        const float* qn = qk + ((size_t)pl << 4);
        float f[10];
#pragma unroll
        for (int n = 0; n < 10; ++n) f[n] = qn[(b + 15 - n) & 15];
        float m = f0;
#pragma unroll
        for (int i = 0; i < 10; ++i) m = fmaxf(m, f[i]);
        float se = expf(f0 - m), fs = f0;
#pragma unroll
        for (int i = 0; i < 10; ++i) { se += expf(f[i] - m); fs += f[i]; }
        contrib = 11.f * (m + logf(se)) - fs;
    }

    __shared__ float red[4];
#pragma unroll
    for (int off = 32; off > 0; off >>= 1) contrib += __shfl_down(contrib, off);
    const int lane = threadIdx.x & 63;
    const int wave = threadIdx.x >> 6;
    if (lane == 0) red[wave] = contrib;
    __syncthreads();
    if (threadIdx.x == 0) atomicAdd(&lacc[k - 1], red[0] + red[1] + red[2] + red[3]);
}

__global__ void finalize_loss_kernel(const float* __restrict__ lacc, float* __restrict__ out1)
{
    int k = threadIdx.x;
    if (k < KSTEPS) {
        float div = (float)((L_ - 2 * (k + 1)) * B_);
        out1[k] = lacc[k] / div;
    }
}

// -------------------- launch --------------------
extern "C" void kernel_launch(void* const* d_in, const int* in_sizes, int n_in,
                              void* d_out, int out_size, void* d_ws, size_t ws_size,
                              hipStream_t stream)
{
    const float* x     = (const float*)d_in[0];
    const float* cw    = (const float*)d_in[1];
    const float* cb    = (const float*)d_in[2];
    const float* gamma = (const float*)d_in[3];
    const float* beta  = (const float*)d_in[4];
    const float* tw    = (const float*)d_in[5];
    const float* tb    = (const float*)d_in[6];
    const int*   perm  = (const int*)d_in[7];

    float* out0 = (float*)d_out;
    float* out1 = out0 + (size_t)B_ * C_ * L_;

    char* ws = (char*)d_ws;
    __hip_bfloat16* Zb = (__hip_bfloat16*)ws;   ws += (size_t)N_ * C_ * 2;
    __hip_bfloat16* Wt = (__hip_bfloat16*)ws;   ws += (size_t)KSTEPS * C_ * C_ * 2;
    float* qt    = (float*)ws;                  ws += (size_t)KSTEPS * QSTR * 4;
    float* ssum  = (float*)ws;                  ws += C_ * 4;
    float* ssq   = (float*)ws;                  ws += C_ * 4;
    float* lacc  = (float*)ws;                  ws += 64 * 4;
    float* scale = (float*)ws;                  ws += C_ * 4;
    float* shift = (float*)ws;                  ws += C_ * 4;

    hipMemsetAsync(ssum, 0, (C_ + C_ + 64) * sizeof(float), stream);

    dim3 gstat(16, 16);
    conv_stats_kernel<<<gstat, 256, 0, stream>>>(x, cw, cb, ssum, ssq);
    bn_finalize_kernel<<<1, 256, 0, stream>>>(ssum, ssq, gamma, beta, scale, shift);

    dim3 gcv(32, 16);
    conv_norm_kernel<<<gcv, 256, 0, stream>>>(x, cw, cb, scale, shift, Zb, out0);

    dim3 gwt(4, 4, KSTEPS);
    wt_kernel<<<gwt, 256, 0, stream>>>(tw, Wt);

    dim3 gq(128, KSTEPS);
    qmfma_kernel<<<gq, 256, 0, stream>>>(Zb, Wt, tb, qt);

    dim3 gl(128, KSTEPS);
    loss_kernel<<<gl, 256, 0, stream>>>(qt, perm, lacc);
    finalize_loss_kernel<<<1, 64, 0, stream>>>(lacc, out1);
}

// Round 5
// 191.950 us; speedup vs baseline: 4.5340x; 1.0633x over previous
//
#include <hip/hip_runtime.h>
#include <hip/hip_bf16.h>
#include <math.h>

constexpr int B_ = 16;
constexpr int T_ = 10240;
constexpr int C_ = 256;
constexpr int KW = 10;
constexpr int L_ = 2047;
constexpr int N_ = B_ * L_;      // 32752
constexpr int KSTEPS = 12;
constexpr float EPS_ = 1e-5f;
constexpr int QSTR = 32768;      // per-k stride of transposed q (2048*16)

typedef short bf16x8 __attribute__((ext_vector_type(8)));
typedef float f32x4  __attribute__((ext_vector_type(4)));

// -------------------- fused: conv+relu+BN-stats  ∪  W-transpose --------------------
// blocks [0,256): stats over (b, 128-l tile); blocks [256,448): wt 64x64 transpose tiles
__global__ __launch_bounds__(256) void stats_wt_kernel(
    const float* __restrict__ x, const float* __restrict__ cw, const float* __restrict__ cb,
    float* __restrict__ ssum, float* __restrict__ ssq,
    const float* __restrict__ tw, __hip_bfloat16* __restrict__ Wt)
{
    __shared__ float smem[64 * 65];
    const int bid = blockIdx.x;
    if (bid < 256) {
        const int b  = bid & 15;
        const int l0 = (bid >> 4) * 128;
        const int cnt = min(128, L_ - l0);
        const int c = threadIdx.x;
        float* xs = smem;
        const float* xb = x + (size_t)b * T_;
        for (int i = threadIdx.x; i < cnt * 5 + 5; i += 256) xs[i] = xb[l0 * 5 + i];
        float w[KW];
#pragma unroll
        for (int j = 0; j < KW; ++j) w[j] = cw[c * KW + j];
        const float bias = cb[c];
        __syncthreads();
        float s = 0.f, s2 = 0.f;
        for (int dl = 0; dl < cnt; ++dl) {
            float v = bias;
#pragma unroll
            for (int j = 0; j < KW; ++j) v = fmaf(xs[dl * 5 + j], w[j], v);
            v = fmaxf(v, 0.f);
            s += v;
            s2 = fmaf(v, v, s2);
        }
        atomicAdd(&ssum[c], s);
        atomicAdd(&ssq[c], s2);
    } else {
        const int idx = bid - 256;            // 0..191
        const int k  = idx >> 4;
        const int c0 = ((idx & 15) >> 2) * 64, j0 = (idx & 3) * 64;
        float (*tile)[65] = (float(*)[65])smem;
        for (int i = threadIdx.x; i < 64 * 64; i += 256) {
            int c = i >> 6, j = i & 63;
            tile[c][j] = tw[((size_t)k * C_ + (c0 + c)) * C_ + j0 + j];
        }
        __syncthreads();
        for (int i = threadIdx.x; i < 64 * 64; i += 256) {
            int j = i >> 6, c = i & 63;
            Wt[((size_t)k * C_ + (j0 + j)) * C_ + c0 + c] = __float2bfloat16(tile[c][j]);
        }
    }
}

// -------------------- finalize BN scale/shift --------------------
__global__ void bn_finalize_kernel(const float* __restrict__ ssum, const float* __restrict__ ssq,
                                   const float* __restrict__ gamma, const float* __restrict__ beta,
                                   float* __restrict__ scale, float* __restrict__ shift)
{
    int c = threadIdx.x;
    const float inv_n = 1.0f / (float)N_;
    float mu  = ssum[c] * inv_n;
    float var = ssq[c] * inv_n - mu * mu;
    float sc  = gamma[c] * rsqrtf(var + EPS_);
    scale[c] = sc;
    shift[c] = beta[c] - mu * sc;
}

// -------------------- conv+relu+normalize → out0 (f32) + Zb (bf16), 32-l tiles -------
__global__ __launch_bounds__(256) void conv_norm_kernel(
    const float* __restrict__ x, const float* __restrict__ cw, const float* __restrict__ cb,
    const float* __restrict__ scale, const float* __restrict__ shift,
    __hip_bfloat16* __restrict__ Zb, float* __restrict__ out0)
{
    const int b  = blockIdx.y;
    const int l0 = blockIdx.x * 32;
    const int cnt = min(32, L_ - l0);
    const int c = threadIdx.x;
    __shared__ float xs[32 * 5 + 8];
    __shared__ float zt[32][257];
    const float* xb = x + (size_t)b * T_;
    for (int i = threadIdx.x; i < cnt * 5 + 5; i += 256) xs[i] = xb[l0 * 5 + i];
    float w[KW];
#pragma unroll
    for (int j = 0; j < KW; ++j) w[j] = cw[c * KW + j];
    const float bias = cb[c];
    const float sc = scale[c], sh = shift[c];
    __syncthreads();
    for (int dl = 0; dl < cnt; ++dl) {
        float v = bias;
#pragma unroll
        for (int j = 0; j < KW; ++j) v = fmaf(xs[dl * 5 + j], w[j], v);
        v = fmaxf(v, 0.f);
        float z = fmaf(v, sc, sh);
        Zb[((size_t)(b * L_ + l0 + dl)) * C_ + c] = __float2bfloat16(z);  // 512B coalesced
        zt[dl][c] = z;                                                     // banks = c%32, free
    }
    __syncthreads();
    // out0: lanes 0..31 = l within tile; each wave-instr writes 2 x 128B row segments
    const int lq  = threadIdx.x & 31;
    const int cr0 = threadIdx.x >> 5;      // 0..7
    if (lq < cnt) {
#pragma unroll
        for (int i = 0; i < 32; ++i) {
            int cr = cr0 * 32 + i;
            out0[((size_t)(b * C_ + cr)) * L_ + l0 + lq] = zt[lq][cr];     // banks lq+cr: 2-way
        }
    }
}

// -------------------- q kernel (MFMA, W-resident, swizzled LDS, 1 barrier/tile) ------
// q_k[i] = rowsum((Z W_k + b) ⊙ Z).  Grid (128,12): block = one k, 8 tiles × 32 rows.
// 4 waves × 64 cols (W in 128 VGPRs). LDS Z-tile: unpadded 512B rows, 16B chunk j of
// row r stored at j ^ (r&7)  → A-frag ds_read_b128 at even-bank BW floor (no 4-way).
__global__ __launch_bounds__(256, 2) void qmfma_kernel(
    const __hip_bfloat16* __restrict__ Zb, const __hip_bfloat16* __restrict__ Wt,
    const float* __restrict__ tb, float* __restrict__ qt)
{
    const int k   = blockIdx.y;
    const int grp = blockIdx.x;
    const __hip_bfloat16* __restrict__ Wk = Wt + (size_t)k * C_ * C_;

    __shared__ __hip_bfloat16 zs[2][32 * 256];
    __shared__ float qacc[4][256];

    const int tid  = threadIdx.x;
    const int lane = tid & 63, wave = tid >> 6;
    const int n16  = lane & 15, quad = lane >> 4;
    const int sw   = n16 & 7;                      // row-swizzle key (same for rt=0/1)

    // ---- W resident: col = 64*wave + ct*16 + n16 ; kk = it*32 + quad*8 + j ----
    bf16x8 wfrag[4][8];
    {
        const __hip_bfloat16* wb = Wk + ((size_t)(64 * wave + n16)) * C_ + quad * 8;
#pragma unroll
        for (int ct = 0; ct < 4; ++ct)
#pragma unroll
            for (int it = 0; it < 8; ++it)
                wfrag[ct][it] = *(const bf16x8*)(wb + ct * 16 * C_ + it * 32);
    }
    float4 bias4[4];
#pragma unroll
    for (int ct = 0; ct < 4; ++ct)
        bias4[ct] = *(const float4*)(tb + k * C_ + 64 * wave + ct * 16 + quad * 4);

    const int row0 = grp * 8 * 32;
    float4 greg[4];

    // stage tile 0 (32 rows × 512B, swizzled)
#pragma unroll
    for (int i = 0; i < 4; ++i) {
        int chunk = tid + i * 256;
        int r = chunk >> 5;
        int rg = row0 + r; if (rg > N_ - 1) rg = N_ - 1;
        greg[i] = *(const float4*)(Zb + (size_t)rg * C_ + (chunk & 31) * 8);
    }
#pragma unroll
    for (int i = 0; i < 4; ++i) {
        int chunk = tid + i * 256;
        int r = chunk >> 5, j = chunk & 31;
        *(float4*)((__hip_bfloat16*)zs[0] + r * 256 + (j ^ (r & 7)) * 8) = greg[i];
    }
    __syncthreads();

    for (int t = 0; t < 8; ++t) {
        const int p = t & 1;

        // prefetch next tile (global → regs); hidden under this tile's MFMA
        if (t < 7) {
            int r0 = row0 + (t + 1) * 32;
#pragma unroll
            for (int i = 0; i < 4; ++i) {
                int chunk = tid + i * 256;
                int r = chunk >> 5;
                int rg = r0 + r; if (rg > N_ - 1) rg = N_ - 1;
                greg[i] = *(const float4*)(Zb + (size_t)rg * C_ + (chunk & 31) * 8);
            }
        }

        f32x4 acc[2][4];
#pragma unroll
        for (int rt = 0; rt < 2; ++rt)
#pragma unroll
            for (int ct = 0; ct < 4; ++ct) acc[rt][ct] = f32x4{0.f, 0.f, 0.f, 0.f};

        const __hip_bfloat16* zsp = (const __hip_bfloat16*)zs[p];
#pragma unroll
        for (int it = 0; it < 8; ++it) {
            const int js = (it * 4 + quad) ^ sw;
            bf16x8 zf0 = *(const bf16x8*)(zsp + n16 * 256 + js * 8);
            bf16x8 zf1 = *(const bf16x8*)(zsp + (n16 + 16) * 256 + js * 8);
#pragma unroll
            for (int ct = 0; ct < 4; ++ct) {
                acc[0][ct] = __builtin_amdgcn_mfma_f32_16x16x32_bf16(
                    wfrag[ct][it], zf0, acc[0][ct], 0, 0, 0);
                acc[1][ct] = __builtin_amdgcn_mfma_f32_16x16x32_bf16(
                    wfrag[ct][it], zf1, acc[1][ct], 0, 0, 0);
            }
        }

        // ---- epilogue: zrow = rt*16+n16 ; wcols = 64w + ct*16 + quad*4 + r ----
#pragma unroll
        for (int rt = 0; rt < 2; ++rt) {
            const int row = rt * 16 + n16;
            float s = 0.f;
#pragma unroll
            for (int ct = 0; ct < 4; ++ct) {
                const int j  = 8 * wave + 2 * ct + (quad >> 1);
                const char* zp = (const char*)zsp + row * 512 + ((j ^ sw) << 4) + (quad & 1) * 8;
                uint2 zz = *(const uint2*)zp;
                float z0 = __uint_as_float(zz.x << 16);
                float z1 = __uint_as_float(zz.x & 0xffff0000u);
                float z2 = __uint_as_float(zz.y << 16);
                float z3 = __uint_as_float(zz.y & 0xffff0000u);
                s = fmaf(acc[rt][ct][0] + bias4[ct].x, z0, s);
                s = fmaf(acc[rt][ct][1] + bias4[ct].y, z1, s);
                s = fmaf(acc[rt][ct][2] + bias4[ct].z, z2, s);
                s = fmaf(acc[rt][ct][3] + bias4[ct].w, z3, s);
            }
            s += __shfl_xor(s, 16);
            s += __shfl_xor(s, 32);
            if (lane < 16) qacc[wave][t * 32 + row] = s;   // wave-private slice
        }

        // write prefetched tile into the inactive buffer
        if (t < 7) {
#pragma unroll
            for (int i = 0; i < 4; ++i) {
                int chunk = tid + i * 256;
                int r = chunk >> 5, j = chunk & 31;
                *(float4*)((__hip_bfloat16*)zs[1 - p] + r * 256 + (j ^ (r & 7)) * 8) = greg[i];
            }
        }
        __syncthreads();
    }

    // ---- block-end: reduce 4 wave partials per row, write transposed qt ----
    {
        int r  = tid;
        int rg = row0 + r;
        if (rg < N_) {
            float qv = qacc[0][r] + qacc[1][r] + qacc[2][r] + qacc[3][r];
            int b = rg / L_;
            int l = rg - b * L_;
            qt[(size_t)k * QSTR + (l << 4) + b] = qv;
        }
    }
}

// -------------------- loss: coalesced gathers from transposed q, LSE, accumulate ------
__global__ __launch_bounds__(256) void loss_kernel(
    const float* __restrict__ qt, const int* __restrict__ perm, float* __restrict__ lacc)
{
    const int k = blockIdx.y + 1;                 // 1..12
    const float* qk = qt + (size_t)(k - 1) * QSTR;
    const int nval = B_ * (L_ - k);
    const int idx = blockIdx.x * 256 + threadIdx.x;

    float contrib = 0.f;
    if (idx < nval) {
        int b = idx & 15;
        int l = k + (idx >> 4);
        float f0 = qk[(l << 4) | b];
        int pl = perm[l];
        const float* qn = qk + ((size_t)pl << 4);
        float f[10];
#pragma unroll
        for (int n = 0; n < 10; ++n) f[n] = qn[(b + 15 - n) & 15];
        float m = f0;
#pragma unroll
        for (int i = 0; i < 10; ++i) m = fmaxf(m, f[i]);
        float se = expf(f0 - m), fs = f0;
#pragma unroll
        for (int i = 0; i < 10; ++i) { se += expf(f[i] - m); fs += f[i]; }
        contrib = 11.f * (m + logf(se)) - fs;
    }

    __shared__ float red[4];
#pragma unroll
    for (int off = 32; off > 0; off >>= 1) contrib += __shfl_down(contrib, off);
    const int lane = threadIdx.x & 63;
    const int wave = threadIdx.x >> 6;
    if (lane == 0) red[wave] = contrib;
    __syncthreads();
    if (threadIdx.x == 0) atomicAdd(&lacc[k - 1], red[0] + red[1] + red[2] + red[3]);
}

__global__ void finalize_loss_kernel(const float* __restrict__ lacc, float* __restrict__ out1)
{
    int k = threadIdx.x;
    if (k < KSTEPS) {
        float div = (float)((L_ - 2 * (k + 1)) * B_);
        out1[k] = lacc[k] / div;
    }
}

// -------------------- launch --------------------
extern "C" void kernel_launch(void* const* d_in, const int* in_sizes, int n_in,
                              void* d_out, int out_size, void* d_ws, size_t ws_size,
                              hipStream_t stream)
{
    const float* x     = (const float*)d_in[0];
    const float* cw    = (const float*)d_in[1];
    const float* cb    = (const float*)d_in[2];
    const float* gamma = (const float*)d_in[3];
    const float* beta  = (const float*)d_in[4];
    const float* tw    = (const float*)d_in[5];
    const float* tb    = (const float*)d_in[6];
    const int*   perm  = (const int*)d_in[7];

    float* out0 = (float*)d_out;
    float* out1 = out0 + (size_t)B_ * C_ * L_;

    char* ws = (char*)d_ws;
    __hip_bfloat16* Zb = (__hip_bfloat16*)ws;   ws += (size_t)N_ * C_ * 2;
    __hip_bfloat16* Wt = (__hip_bfloat16*)ws;   ws += (size_t)KSTEPS * C_ * C_ * 2;
    float* qt    = (float*)ws;                  ws += (size_t)KSTEPS * QSTR * 4;
    float* ssum  = (float*)ws;                  ws += C_ * 4;
    float* ssq   = (float*)ws;                  ws += C_ * 4;
    float* lacc  = (float*)ws;                  ws += 64 * 4;
    float* scale = (float*)ws;                  ws += C_ * 4;
    float* shift = (float*)ws;                  ws += C_ * 4;

    hipMemsetAsync(ssum, 0, (C_ + C_ + 64) * sizeof(float), stream);

    stats_wt_kernel<<<448, 256, 0, stream>>>(x, cw, cb, ssum, ssq, tw, Wt);
    bn_finalize_kernel<<<1, 256, 0, stream>>>(ssum, ssq, gamma, beta, scale, shift);

    dim3 gcv(64, 16);
    conv_norm_kernel<<<gcv, 256, 0, stream>>>(x, cw, cb, scale, shift, Zb, out0);

    dim3 gq(128, KSTEPS);
    qmfma_kernel<<<gq, 256, 0, stream>>>(Zb, Wt, tb, qt);

    dim3 gl(128, KSTEPS);
    loss_kernel<<<gl, 256, 0, stream>>>(qt, perm, lacc);
    finalize_loss_kernel<<<1, 64, 0, stream>>>(lacc, out1);
}